// Round 9
// baseline (1067.053 us; speedup 1.0000x reference)
//
#include <hip/hip_runtime.h>
#include <hip/hip_bf16.h>
#include <math.h>

// Static maxima (LDS sizing); actual dims derived at runtime from in_sizes.
#define LMAX 8192
#define KGAUSS 25

#define PI_F 3.14159265358979323846f
#define TWO_PI_F 6.28318530717958647692f

typedef __hip_bfloat16 bf16;
typedef unsigned short u16;
typedef short bf16x8 __attribute__((ext_vector_type(8)));
typedef float f32x4 __attribute__((ext_vector_type(4)));

__device__ __forceinline__ float b2f(bf16 v) { return __bfloat162float(v); }
__device__ __forceinline__ bf16 f2b(float v) { return __float2bfloat16(v); }
__device__ __forceinline__ float rdv(const void* p, long i, int isb) {
  return isb ? b2f(((const bf16*)p)[i]) : ((const float*)p)[i];
}

__device__ __forceinline__ void async16(const void* g, void* l) {
#if __has_builtin(__builtin_amdgcn_global_load_lds)
  __builtin_amdgcn_global_load_lds((const __attribute__((address_space(1))) void*)g,
                                   (__attribute__((address_space(3))) void*)l, 16, 0, 0);
#else
  *(uint4*)l = *(const uint4*)g;
#endif
}

// ---------------- dtype detector (inputs may be bf16 or f32) ----------------
__global__ void k_detect(const unsigned* ls, int* flag) {
  unsigned w = ls[0];
  flag[0] = ((w >> 16) == (w & 0xffffu)) ? 1 : 0;
}

__global__ void k_to_bf16(const void* __restrict__ in, bf16* __restrict__ out, long n,
                          const int* __restrict__ flag) {
  long i = (long)blockIdx.x * blockDim.x + threadIdx.x;
  if (i >= n) return;
  out[i] = (*flag) ? ((const bf16*)in)[i] : f2b(((const float*)in)[i]);
}

// Small params -> f32 workspace, FIXED slots:
// xb@0, ib@2048, ls@4096, pw@4352, al@8448, ph@8704, ps@8960, b1@8961, b2@8962
__global__ void k_params(const void* xb, const void* ib, const void* ls, const void* pw,
                         const void* al, const void* ph, const void* ps, const void* b1,
                         const void* b2, float* pf, const int* flag, int D, int C, int KP) {
  int i = blockIdx.x * blockDim.x + threadIdx.x;
  if (i >= 16384) return;
  int isb = *flag;
  float v = 0.0f;
  if (i < D)                              v = rdv(xb, i, isb);
  else if (i >= 2048 && i < 2048 + D)     v = rdv(ib, i - 2048, isb);
  else if (i >= 4096 && i < 4096 + C)     v = rdv(ls, i - 4096, isb);
  else if (i >= 4352 && i < 4352 + C*KP)  v = rdv(pw, i - 4352, isb);
  else if (i >= 8448 && i < 8448 + C)     v = rdv(al, i - 8448, isb);
  else if (i >= 8704 && i < 8704 + C)     v = rdv(ph, i - 8704, isb);
  else if (i == 8960)                     v = rdv(ps, 0, isb);
  else if (i == 8961)                     v = rdv(b1, 0, isb);
  else if (i == 8962)                     v = rdv(b2, 0, isb);
  pf[i] = v;
}

__global__ void k_twiddle(float2* tw, int L) {
  int j = blockIdx.x * blockDim.x + threadIdx.x;
  if (j < L / 2) {
    double a = 6.283185307179586476925286766559 * (double)j / (double)L;
    tw[j] = make_float2((float)cos(a), (float)sin(a));
  }
}

// ---------------- transpose W[K][N] -> Wt[N][K] bf16 ----------------
__global__ __launch_bounds__(256) void k_transpose(const void* __restrict__ in,
    bf16* __restrict__ out, const int* __restrict__ flag, int K, int N) {
  __shared__ u16 tile[64][65];
  int isb = *flag;
  int r0 = blockIdx.x * 64, c0 = blockIdx.y * 64;
  int t = threadIdx.x;
#pragma unroll
  for (int i = 0; i < 16; ++i) {
    int idx = t + i * 256;
    int r = idx >> 6, cc = idx & 63;
    int gr = r0 + r; gr = gr < K ? gr : K - 1;
    int gc = c0 + cc; gc = gc < N ? gc : N - 1;
    size_t gi = (size_t)gr * N + gc;
    u16 v;
    if (isb) v = ((const u16*)in)[gi];
    else { bf16 h = f2b(((const float*)in)[gi]); v = *(u16*)&h; }
    tile[r][cc] = v;
  }
  __syncthreads();
#pragma unroll
  for (int i = 0; i < 16; ++i) {
    int idx = t + i * 256;
    int a = idx >> 6, bb = idx & 63;
    if (c0 + a < N && r0 + bb < K)
      ((u16*)out)[(size_t)(c0 + a) * K + (r0 + bb)] = tile[bb][a];
  }
}

// ---------------- gaussian trend / seasonal ----------------
__global__ __launch_bounds__(256) void k_decomp(const void* __restrict__ x,
    const int* __restrict__ flag, const float* __restrict__ pf,
    float* __restrict__ seasonal, float* __restrict__ trend0, int C, int L) {
  __shared__ float xs[LMAX];
  int bc = blockIdx.x;
  int c = bc % C, b = bc / C;
  int t = threadIdx.x;
  int isb = *flag;
  for (int i = t; i < L; i += 256) xs[i] = rdv(x, (size_t)bc * L + i, isb);
  float sigma = expf(pf[4096 + c]) + 1e-6f;
  float inv2s2 = 1.0f / (2.0f * sigma * sigma);
  float g[KGAUSS];
  float gs = 0.0f;
  for (int j = 0; j < KGAUSS; ++j) {
    float d = (float)(j - 12);
    float v = expf(-(d * d) * inv2s2);
    g[j] = v; gs += v;
  }
  float ginv = 1.0f / (gs + 1e-12f);
  for (int j = 0; j < KGAUSS; ++j) g[j] *= ginv;
  __syncthreads();
  for (int i = t; i < L; i += 256) {
    float acc = 0.0f;
#pragma unroll
    for (int j = 0; j < KGAUSS; ++j) {
      int idx = i + j - 12;
      idx = idx < 0 ? -idx : (idx >= L ? 2 * L - 2 - idx : idx);
      acc += g[j] * xs[idx];
    }
    seasonal[(size_t)bc * L + i] = xs[i] - acc;
    if (b == 0) trend0[(size_t)c * L + i] = acc;
  }
}

// ---------------- FFT (radix-2 DIT, L-pt, LDS) ----------------
__device__ __forceinline__ void bitrev_permute(float2* z, int t, int L, int lg) {
  for (int i = t; i < L; i += 256) {
    int r = (int)(__brev((unsigned)i) >> (32 - lg));
    if (i < r) { float2 tmp = z[i]; z[i] = z[r]; z[r] = tmp; }
  }
  __syncthreads();
}

__device__ __forceinline__ void fft_stages(float2* z, const float2* __restrict__ tw,
                                           int t, int L, int lg, int inverse) {
  for (int s = 1; s <= lg; ++s) {
    int half = 1 << (s - 1);
    for (int q = t; q < (L >> 1); q += 256) {
      int pos = q & (half - 1);
      int i0 = ((q >> (s - 1)) << s) + pos;
      int i1 = i0 + half;
      float2 w = tw[pos << (lg - s)];
      float wy = inverse ? w.y : -w.y;
      float2 b = z[i1];
      float br = b.x * w.x - b.y * wy;
      float bi = b.x * wy + b.y * w.x;
      float2 a = z[i0];
      z[i0] = make_float2(a.x + br, a.y + bi);
      z[i1] = make_float2(a.x - br, a.y - bi);
    }
    __syncthreads();
  }
}

__global__ __launch_bounds__(256) void k_hilbert(float* __restrict__ sp,
    const float2* __restrict__ tw, int L, int lg) {
  __shared__ float2 z[LMAX];  // 64KB
  float* row = sp + (size_t)blockIdx.x * L;
  int t = threadIdx.x;
  for (int i = t; i < L; i += 256) z[i] = make_float2(row[i], 0.0f);
  __syncthreads();
  bitrev_permute(z, t, L, lg);
  fft_stages(z, tw, t, L, lg, 0);
  float s1 = 1.0f / (float)L, s2 = 2.0f / (float)L;
  int h = L >> 1;
  for (int i = t; i < L; i += 256) {
    float sc = (i == 0 || i == h) ? s1 : (i < h ? s2 : 0.0f);
    z[i].x *= sc; z[i].y *= sc;
  }
  __syncthreads();
  bitrev_permute(z, t, L, lg);
  fft_stages(z, tw, t, L, lg, 1);
  for (int i = t; i < L; i += 256) {
    float2 v = z[i];
    row[i] = atan2f(v.y, v.x);
  }
}

// ---------------- unwrap (integer-k scan) + corrector conv + I ----------------
__global__ __launch_bounds__(256) void k_unwrap_I(const float* __restrict__ phase_all,
    const float* __restrict__ trend0, const float* __restrict__ pf,
    bf16* __restrict__ I, int C, int L, int KP) {
  __shared__ float p[LMAX];
  __shared__ int ksum[256];
  int bc = blockIdx.x;
  int c = bc % C;
  int t = threadIdx.x;
  int chunk = L >> 8;
  const float* prow = phase_all + (size_t)bc * L;
  for (int i = t; i < L; i += 256) p[i] = prow[i];
  __syncthreads();
  int start = t * chunk;
  float prev0 = (t > 0) ? p[start - 1] : 0.0f;
  int kacc = 0;
  {
    float prev = prev0;
    for (int ii = 0; ii < chunk; ++ii) {
      int i = start + ii;
      float cur = p[i];
      if (i > 0) {
        float d = cur - prev;
        int k = (int)floorf((d + PI_F) * (1.0f / TWO_PI_F));
        float m = d - TWO_PI_F * (float)k;
        if (m == -PI_F && d > 0.0f) k -= 1;
        kacc -= k;
      }
      prev = cur;
    }
  }
  ksum[t] = kacc;
  __syncthreads();
  if (t == 0) {
    int run = 0;
    for (int i = 0; i < 256; ++i) { int v = ksum[i]; ksum[i] = run; run += v; }
  }
  __syncthreads();
  {
    int run = ksum[t];
    float prev = prev0;
    for (int ii = 0; ii < chunk; ++ii) {
      int i = start + ii;
      float cur = p[i];
      if (i > 0) {
        float d = cur - prev;
        int k = (int)floorf((d + PI_F) * (1.0f / TWO_PI_F));
        float m = d - TWO_PI_F * (float)k;
        if (m == -PI_F && d > 0.0f) k -= 1;
        run -= k;
      }
      prev = cur;
      p[i] = cur + TWO_PI_F * (float)run;
    }
  }
  __syncthreads();
  float wz[32];
  float mean = 0.0f;
  for (int j = 0; j < KP; ++j) { wz[j] = pf[4352 + c * KP + j]; mean += wz[j]; }
  mean /= (float)KP;
  for (int j = 0; j < KP; ++j) wz[j] -= mean;
  int hk = KP / 2;
  float tanh_s = tanhf(pf[8960]);
  float alpha = log1pf(expf(pf[8448 + c])) + 1e-6f;
  float beta1 = log1pf(expf(pf[8961])) + 1e-6f;
  float beta2 = log1pf(expf(pf[8962])) + 1e-6f;
  float phi0c = pf[8704 + c];
  const float* trow = trend0 + (size_t)c * L;
  bf16* Irow = I + (size_t)bc * L;
  for (int i = t; i < L; i += 256) {
    float pc_center = p[i];
    float delta = 0.0f;
    for (int j = 0; j < KP; ++j) {
      int idx = i + j - hk;
      idx = idx < 0 ? -idx : (idx >= L ? 2 * L - 2 - idx : idx);
      delta += wz[j] * (p[idx] - pc_center);  // Sum(wz)=0 => equals ref conv
    }
    float phi = pc_center + tanh_s * delta + phi0c;
    float T = trow[i];
    T = fminf(10.0f, fmaxf(-10.0f, T));
    float A = alpha * (beta1 * log1pf(expf(beta2 * T)));
    Irow[i] = f2b(A * cosf(phi));
  }
}

// ---------------- MFMA GEMM: C[M,D] = gelu(A[M,L] @ B + bias), f32 OUTPUT ----------
// (R8 discovery: d_out is float32 — all prior rounds wrote bf16 and were compared
//  misaligned. Epilogue now stores f32.)
__global__ __launch_bounds__(256) void k_gemm(const bf16* __restrict__ Abf,
    const bf16* __restrict__ Btbf, const float* __restrict__ bias,
    float* __restrict__ Cout, int M, int L, int D) {
  __shared__ __align__(16) u16 As[128 * 32];
  __shared__ __align__(16) u16 Bs[128 * 32];
  const u16* Ag = (const u16*)Abf;
  const u16* Bg = (const u16*)Btbf;
  int m0 = blockIdx.x * 128, n0 = blockIdx.y * 128;
  int t = threadIdx.x;
  int l = t & 63, w = t >> 6;
  int wm = (w >> 1) * 64, wn = (w & 1) * 64;
  int lr = l & 15, lq = l >> 4;
  f32x4 acc[4][4];
  f32x4 z4 = 0.0f;
  for (int i = 0; i < 4; ++i)
    for (int j = 0; j < 4; ++j) acc[i][j] = z4;

  for (int k0 = 0; k0 < L; k0 += 32) {
#pragma unroll
    for (int q = 0; q < 2; ++q) {
      int chunk = q * 256 + t;
      int row = chunk >> 2, kc = chunk & 3;
      int ar = m0 + row; ar = ar < M ? ar : M - 1;
      int br = n0 + row; br = br < D ? br : D - 1;
      async16(Ag + (size_t)ar * L + (k0 + kc * 8), As + chunk * 8);
      async16(Bg + (size_t)br * L + (k0 + kc * 8), Bs + chunk * 8);
    }
    __syncthreads();
    bf16x8 af[4], bfr[4];
#pragma unroll
    for (int i = 0; i < 4; ++i) {
      af[i]  = *(const bf16x8*)(As + (wm + i * 16 + lr) * 32 + lq * 8);
      bfr[i] = *(const bf16x8*)(Bs + (wn + i * 16 + lr) * 32 + lq * 8);
    }
#pragma unroll
    for (int i = 0; i < 4; ++i)
#pragma unroll
      for (int j = 0; j < 4; ++j)
        acc[i][j] = __builtin_amdgcn_mfma_f32_16x16x32_bf16(af[i], bfr[j], acc[i][j], 0, 0, 0);
    __syncthreads();
  }
#pragma unroll
  for (int i = 0; i < 4; ++i) {
    int rowb = m0 + wm + i * 16 + lq * 4;
#pragma unroll
    for (int j = 0; j < 4; ++j) {
      int gcol = n0 + wn + j * 16 + lr;
      if (gcol < D) {
        float bv = bias[gcol];
#pragma unroll
        for (int r = 0; r < 4; ++r) {
          int grow = rowb + r;
          if (grow < M) {
            float v = acc[i][j][r] + bv;
            float ge = 0.5f * v * (1.0f + erff(v * 0.70710678118654752f));
            Cout[(size_t)grow * D + gcol] = ge;   // float32 store
          }
        }
      }
    }
  }
}

// ---------------- launcher ----------------
static inline int cdiv_i(long a, long b) { return (int)((a + b - 1) / b); }

extern "C" void kernel_launch(void* const* d_in, const int* in_sizes, int n_in,
                              void* d_out, int out_size, void* d_ws, size_t ws_size,
                              hipStream_t stream) {
  // Documented dict order (verified positionally R6): 0 x_input,1 x_w,2 x_b,3 i_w,
  // 4 i_b,5 log_sigma,6 pc_weight,7 pc_strength,8 alpha_log,9 phi0,10 b1,11 b2.
  // R8 discovery: d_out is FLOAT32 (bf16 marker in low half-word was invisible).
  long B = 64, C = 21, L = 8192, D = 512, KP = 15;
  if (n_in == 12) {
    long Sx = in_sizes[0], Sw = in_sizes[1], Sb = in_sizes[2];
    long Sls = in_sizes[5], Spw = in_sizes[6];
    if (Sb > 0 && Sw % Sb == 0 && Sls > 0 && Spw % Sls == 0) {
      long Lc = Sw / Sb, KPc = Spw / Sls;
      if (Lc >= 256 && Lc <= LMAX && !(Lc & (Lc - 1)) && (KPc & 1) && KPc <= 31 &&
          Sx % (Sls * Lc) == 0) {
        L = Lc; D = Sb; C = Sls; KP = KPc; B = Sx / (Sls * Lc);
      }
    }
  }
  long M = B * C;
  int lg = 0; while ((1L << lg) < L) ++lg;

  const void* x_input = d_in[0];
  const void* x_w     = d_in[1];
  const void* x_b     = d_in[2];
  const void* i_w     = d_in[3];
  const void* i_b     = d_in[4];
  const void* lsg     = d_in[5];
  const void* pw      = d_in[6];
  const void* ps      = d_in[7];
  const void* al      = d_in[8];
  const void* ph      = d_in[9];
  const void* b1      = d_in[10];
  const void* b2      = d_in[11];

  char* ws = (char*)d_ws;
  size_t off = 0;
  auto take = [&](size_t bytes) { size_t o = off; off = (off + bytes + 255) & ~(size_t)255; return o; };
  float*  seasonal = (float*)(ws + take((size_t)M * L * 4));
  float*  trend0   = (float*)(ws + take((size_t)C * L * 4));
  bf16*   Ibuf     = (bf16*)(ws + take((size_t)M * L * 2));
  float2* tw       = (float2*)(ws + take((size_t)(L / 2) * 8));
  float*  pf       = (float*)(ws + take(65536));
  int*    flag     = (int*)(ws + take(256));
  bf16*   Xb       = (bf16*)(ws + take((size_t)M * L * 2));
  bf16*   Btx      = (bf16*)(ws + take((size_t)D * L * 2));
  bf16*   Bti      = (bf16*)(ws + take((size_t)D * L * 2));
  if (ws_size < off) return;

  k_detect<<<1, 1, 0, stream>>>((const unsigned*)lsg, flag);
  k_params<<<64, 256, 0, stream>>>(x_b, i_b, lsg, pw, al, ph, ps, b1, b2, pf, flag,
                                   (int)D, (int)C, (int)KP);
  k_twiddle<<<cdiv_i(L / 2, 256), 256, 0, stream>>>(tw, (int)L);

  k_to_bf16<<<cdiv_i(M * L, 256), 256, 0, stream>>>(x_input, Xb, M * L, flag);
  k_transpose<<<dim3(cdiv_i(L, 64), cdiv_i(D, 64)), 256, 0, stream>>>(x_w, Btx, flag,
                                                                      (int)L, (int)D);
  k_transpose<<<dim3(cdiv_i(L, 64), cdiv_i(D, 64)), 256, 0, stream>>>(i_w, Bti, flag,
                                                                      (int)L, (int)D);

  k_decomp<<<(int)M, 256, 0, stream>>>(x_input, flag, pf, seasonal, trend0, (int)C, (int)L);
  k_hilbert<<<(int)M, 256, 0, stream>>>(seasonal, tw, (int)L, lg);
  k_unwrap_I<<<(int)M, 256, 0, stream>>>(seasonal, trend0, pf, Ibuf, (int)C, (int)L, (int)KP);

  float* out0 = (float*)d_out;
  float* out1 = out0 + (size_t)M * D;
  k_gemm<<<dim3(cdiv_i(M, 128), cdiv_i(D, 128)), 256, 0, stream>>>(
      Xb, Btx, pf + 0, out0, (int)M, (int)L, (int)D);
  k_gemm<<<dim3(cdiv_i(M, 128), cdiv_i(D, 128)), 256, 0, stream>>>(
      Ibuf, Bti, pf + 2048, out1, (int)M, (int)L, (int)D);
}